// Round 1
// baseline (122.954 us; speedup 1.0000x reference)
//
#include <hip/hip_runtime.h>

#define IMG_W 2048
#define NUM_NODES 255
#define DEPTH 7
#define NLEAF 128
#define NODE_STRIDE 68   // padded floats per node row in LDS (breaks bank alignment)
#define S_STRIDE 68

// ---------------- Phase A: descend tree per patch, accumulate per-leaf sums ----
__global__ __launch_bounds__(256) void phaseA(const float* __restrict__ img,
                                              const float* __restrict__ nodes,
                                              float* __restrict__ leaf_out,
                                              float* __restrict__ S_partial,
                                              unsigned* __restrict__ cnt_partial)
{
    __shared__ float nds[NUM_NODES * NODE_STRIDE];   // 69360 B
    __shared__ float Sl[NLEAF * S_STRIDE];           // 34816 B
    __shared__ unsigned cntl[NLEAF];

    const int t = threadIdx.x;
    const int b = blockIdx.x;

    for (int i = t; i < NLEAF * S_STRIDE; i += 256) Sl[i] = 0.0f;
    if (t < NLEAF) cntl[t] = 0;

    // cooperative load of the 255x64 node table into padded LDS rows
    const float4* ng = (const float4*)nodes;
    for (int i = t; i < NUM_NODES * 16; i += 256) {
        int row = i >> 4, q = i & 15;
        float4 v = ng[i];
        *(float4*)&nds[row * NODE_STRIDE + q * 4] = v;
    }
    __syncthreads();

    // my patch: p = r*256 + c ; pixel (r*8+ki, c*8+kj)
    const int p = b * 256 + t;
    const int r = p >> 8, c = p & 255;
    float4 xv[16];
    #pragma unroll
    for (int ki = 0; ki < 8; ++ki) {
        const float4* rowp = (const float4*)(img + (size_t)(r * 8 + ki) * IMG_W + c * 8);
        xv[ki * 2 + 0] = rowp[0];
        xv[ki * 2 + 1] = rowp[1];
    }

    int cur = 0;
    for (int lvl = 0; lvl < DEPTH; ++lvl) {
        const int c0 = 2 * cur + 1;
        const float* n0 = &nds[c0 * NODE_STRIDE];
        const float* n1 = n0 + NODE_STRIDE;
        float s0 = 0.f, s1 = 0.f;
        #pragma unroll
        for (int q = 0; q < 16; ++q) {
            float4 a  = *(const float4*)&n0[q * 4];
            float4 bb = *(const float4*)&n1[q * 4];
            float4 x  = xv[q];
            float d;
            d = a.x - x.x; s0 += d * d;  d = bb.x - x.x; s1 += d * d;
            d = a.y - x.y; s0 += d * d;  d = bb.y - x.y; s1 += d * d;
            d = a.z - x.z; s0 += d * d;  d = bb.z - x.z; s1 += d * d;
            d = a.w - x.w; s0 += d * d;  d = bb.w - x.w; s1 += d * d;
        }
        cur = (s1 < s0) ? (c0 + 1) : c0;   // ref: d1 < d0 picks c1 (strict)
    }

    leaf_out[p] = (float)cur;              // leaf node index 127..254
    const int L = cur - 127;

    // accumulate patch into per-leaf LDS sums
    #pragma unroll
    for (int q = 0; q < 16; ++q) {
        float* dst = &Sl[L * S_STRIDE + q * 4];
        float4 x = xv[q];
        atomicAdd(dst + 0, x.x);
        atomicAdd(dst + 1, x.y);
        atomicAdd(dst + 2, x.z);
        atomicAdd(dst + 3, x.w);
    }
    atomicAdd(&cntl[L], 1u);
    __syncthreads();

    // flush block partials (unpadded layout) to workspace
    float* Sp = S_partial + (size_t)b * (NLEAF * 64);
    for (int i = t; i < NLEAF * 16; i += 256) {
        int row = i >> 4, q = i & 15;
        float4 v = *(const float4*)&Sl[row * S_STRIDE + q * 4];
        *(float4*)&Sp[row * 64 + q * 4] = v;
    }
    if (t < NLEAF) cnt_partial[b * NLEAF + t] = cntl[t];
}

// ---------------- reduce partials ----------------
__global__ __launch_bounds__(256) void reduceS(const float* __restrict__ S_partial,
                                               const unsigned* __restrict__ cnt_partial,
                                               float* __restrict__ S,
                                               float* __restrict__ cnt)
{
    const int tid = blockIdx.x * 256 + threadIdx.x;  // 8192 total
    float s = 0.f;
    for (int b = 0; b < 256; ++b) s += S_partial[(size_t)b * 8192 + tid];
    S[tid] = s;
    if (tid < NLEAF) {
        unsigned cc = 0;
        for (int b = 0; b < 256; ++b) cc += cnt_partial[b * NLEAF + tid];
        cnt[tid] = (float)cc;
    }
}

// ---------------- node update: tiny 254x64x128 contraction ----------------
__global__ __launch_bounds__(64) void updateNodes(const float* __restrict__ nodes,
                                                  const float* __restrict__ S,
                                                  const float* __restrict__ cnt,
                                                  float* __restrict__ out)
{
    const int n = blockIdx.x;      // 0..254 (node id)
    const int k = threadIdx.x;     // 0..63
    if (n == 0) { out[k] = nodes[k]; return; }

    const int pos = n + 1;                 // 1-based heap index
    const int Ln = 31 - __clz(pos);        // node level, 1..7
    float su = 0.f, sc = 0.f;
    for (int L = 0; L < NLEAF; ++L) {
        const int a = (128 + L) >> (7 - Ln);   // leaf's ancestor at level Ln (1-based)
        const int x = pos ^ a;
        // state = depth of LCA(node, leaf) = number of matching path levels
        const int state = (x == 0) ? Ln : (Ln - (31 - __clz(x)) - 1);
        // lrates[i] = 0.3f * 2^(i-7), exact pow2 scaling matches the reference
        const float lr = 0.3f * ((float)(1 << state) * (1.0f / 128.0f));
        su += lr * S[L * 64 + k];
        sc += lr * cnt[L];
    }
    const float invP = 1.0f / 65536.0f;
    const float nd = nodes[n * 64 + k];
    out[n * 64 + k] = nd + su * invP - (sc * invP) * nd;
}

extern "C" void kernel_launch(void* const* d_in, const int* in_sizes, int n_in,
                              void* d_out, int out_size, void* d_ws, size_t ws_size,
                              hipStream_t stream)
{
    const float* img   = (const float*)d_in[0];   // 2048*2048 f32
    const float* nodes = (const float*)d_in[1];   // 255*64 f32

    float* out_nodes = (float*)d_out;                 // 255*64
    float* out_leaf  = out_nodes + NUM_NODES * 64;    // 65536 (leaf index as f32)

    float*    S_partial   = (float*)d_ws;                          // 256*128*64 f32 = 8 MB
    unsigned* cnt_partial = (unsigned*)(S_partial + 256 * 8192);   // 256*128 u32
    float*    S           = (float*)(cnt_partial + 256 * NLEAF);   // 128*64
    float*    cnt         = S + 8192;                              // 128

    phaseA<<<256, 256, 0, stream>>>(img, nodes, out_leaf, S_partial, cnt_partial);
    reduceS<<<32, 256, 0, stream>>>(S_partial, cnt_partial, S, cnt);
    updateNodes<<<NUM_NODES, 64, 0, stream>>>(nodes, S, cnt, out_nodes);
}

// Round 2
// 114.646 us; speedup vs baseline: 1.0725x; 1.0725x over previous
//
#include <hip/hip_runtime.h>

#define IMG_W 2048
#define NUM_NODES 255
#define DEPTH 7
#define NLEAF 128
#define NODE_STRIDE 68   // padded floats per LDS row: base bank = 4*row&31, spreads groups
#define S_STRIDE 68
#define OVERLAY_FLOATS (256 * NODE_STRIDE)   // 17408 floats; holds nodes (255*68=17340) then patch stage (256*68)

// ---------------- zero-init S / cnt (ws is re-poisoned every call) ----------
__global__ __launch_bounds__(256) void zeroS(float* __restrict__ S, unsigned* __restrict__ cnt)
{
    const int i = blockIdx.x * 256 + threadIdx.x;
    if (i < NLEAF * 64) S[i] = 0.0f;
    if (i < NLEAF) cnt[i] = 0u;
}

// ---------------- Phase A: descend tree, accumulate per-leaf sums ------------
__global__ __launch_bounds__(256) void phaseA(const float* __restrict__ img,
                                              const float* __restrict__ nodes,
                                              float* __restrict__ leaf_out,
                                              float* __restrict__ S,
                                              unsigned* __restrict__ cnt)
{
    __shared__ float smem[OVERLAY_FLOATS + NLEAF * S_STRIDE];  // 104448 B
    __shared__ unsigned cntl[NLEAF];
    float* nds = smem;                    // node table; reused as patch stage after descent
    float* Sl  = smem + OVERLAY_FLOATS;   // per-leaf accumulators

    const int t = threadIdx.x;
    const int b = blockIdx.x;

    for (int i = t; i < NLEAF * S_STRIDE; i += 256) Sl[i] = 0.0f;
    if (t < NLEAF) cntl[t] = 0u;

    // cooperative load of the 255x64 node table into padded LDS rows
    const float4* ng = (const float4*)nodes;
    for (int i = t; i < NUM_NODES * 16; i += 256) {
        const int row = i >> 4, q = i & 15;
        *(float4*)&nds[row * NODE_STRIDE + q * 4] = ng[i];
    }
    __syncthreads();

    // my patch: p = r*256 + c ; pixel (r*8+ki, c*8+kj). Block reads 8 contiguous image rows.
    const int p = b * 256 + t;
    const int r = p >> 8, c = p & 255;
    float4 xv[16];
    #pragma unroll
    for (int ki = 0; ki < 8; ++ki) {
        const float4* rowp = (const float4*)(img + (size_t)(r * 8 + ki) * IMG_W + c * 8);
        xv[ki * 2 + 0] = rowp[0];
        xv[ki * 2 + 1] = rowp[1];
    }

    int cur = 0;
    #pragma unroll
    for (int lvl = 0; lvl < DEPTH; ++lvl) {
        const int c0 = 2 * cur + 1;
        const float* n0 = &nds[c0 * NODE_STRIDE];
        const float* n1 = n0 + NODE_STRIDE;
        float s0 = 0.f, s1 = 0.f;
        #pragma unroll
        for (int q = 0; q < 16; ++q) {
            const float4 a  = *(const float4*)&n0[q * 4];
            const float4 bb = *(const float4*)&n1[q * 4];
            const float4 x  = xv[q];
            float d;
            d = a.x - x.x; s0 += d * d;  d = bb.x - x.x; s1 += d * d;
            d = a.y - x.y; s0 += d * d;  d = bb.y - x.y; s1 += d * d;
            d = a.z - x.z; s0 += d * d;  d = bb.z - x.z; s1 += d * d;
            d = a.w - x.w; s0 += d * d;  d = bb.w - x.w; s1 += d * d;
        }
        cur = (s1 < s0) ? (c0 + 1) : c0;   // ref: d1 < d0 picks c1 (strict)
    }

    leaf_out[p] = (float)cur;              // leaf node index 127..254
    const int L = cur - 127;

    __syncthreads();                       // all descents done with nds -> safe to overlay

    // stage my patch into my own LDS row (thread-private region, no barrier needed to read back)
    float* st = &nds[t * NODE_STRIDE];
    #pragma unroll
    for (int q = 0; q < 16; ++q) *(float4*)&st[q * 4] = xv[q];

    // accumulate with per-lane permuted element order: e = (5*lane + s) & 63.
    // 5 is odd -> at every step all 64 lanes hit 64 DISTINCT elements of the leaf row:
    // no same-address serialization, exactly 2 lanes/bank (free).
    float* rowS = &Sl[L * S_STRIDE];
    const int lane5 = 5 * (t & 63);
    #pragma unroll 8
    for (int s = 0; s < 64; ++s) {
        const int e = (lane5 + s) & 63;
        atomicAdd(&rowS[e], st[e]);
    }
    atomicAdd(&cntl[L], 1u);
    __syncthreads();

    // flush block-local sums straight to global S (lane-distinct addresses, skip zeros)
    for (int i = t; i < NLEAF * 64; i += 256) {
        const float v = Sl[(i >> 6) * S_STRIDE + (i & 63)];
        if (v != 0.0f) atomicAdd(&S[i], v);
    }
    if (t < NLEAF && cntl[t] != 0u) atomicAdd(&cnt[t], cntl[t]);
}

// ---------------- node update: tiny 254x64x128 contraction -------------------
__global__ __launch_bounds__(64) void updateNodes(const float* __restrict__ nodes,
                                                  const float* __restrict__ S,
                                                  const unsigned* __restrict__ cnt,
                                                  float* __restrict__ out)
{
    const int n = blockIdx.x;      // 0..254 (node id)
    const int k = threadIdx.x;     // 0..63
    if (n == 0) { out[k] = nodes[k]; return; }   // whole block exits together

    __shared__ float lrL[NLEAF];
    __shared__ float cl[NLEAF];

    const int pos = n + 1;                 // 1-based heap index
    const int Ln = 31 - __clz(pos);        // node level, 1..7
    for (int L = k; L < NLEAF; L += 64) {
        const int a = (128 + L) >> (7 - Ln);   // leaf's ancestor at level Ln (1-based)
        const int x = pos ^ a;
        const int state = (x == 0) ? Ln : (Ln - (31 - __clz(x)) - 1);
        lrL[L] = 0.3f * ((float)(1 << state) * (1.0f / 128.0f));
        cl[L]  = (float)cnt[L];
    }
    __syncthreads();

    float su = 0.f, sc = 0.f;
    #pragma unroll 8
    for (int L = 0; L < NLEAF; ++L) {
        const float lr = lrL[L];
        su = fmaf(lr, S[L * 64 + k], su);
        sc = fmaf(lr, cl[L], sc);
    }
    const float invP = 1.0f / 65536.0f;
    const float nd = nodes[n * 64 + k];
    out[n * 64 + k] = nd + su * invP - (sc * invP) * nd;
}

extern "C" void kernel_launch(void* const* d_in, const int* in_sizes, int n_in,
                              void* d_out, int out_size, void* d_ws, size_t ws_size,
                              hipStream_t stream)
{
    const float* img   = (const float*)d_in[0];   // 2048*2048 f32
    const float* nodes = (const float*)d_in[1];   // 255*64 f32

    float* out_nodes = (float*)d_out;                 // 255*64
    float* out_leaf  = out_nodes + NUM_NODES * 64;    // 65536 (leaf index as f32)

    float*    S   = (float*)d_ws;                     // 128*64 f32
    unsigned* cnt = (unsigned*)(S + NLEAF * 64);      // 128 u32

    zeroS<<<33, 256, 0, stream>>>(S, cnt);
    phaseA<<<256, 256, 0, stream>>>(img, nodes, out_leaf, S, cnt);
    updateNodes<<<NUM_NODES, 64, 0, stream>>>(nodes, S, cnt, out_nodes);
}